// Round 6
// baseline (332.014 us; speedup 1.0000x reference)
//
#include <hip/hip_runtime.h>
#include <stdint.h>

#define D_IN 256
#define D_OUT 128
#define MAXB 800     // max dst-buckets of 128 nodes (N <= 102400)
#define NCHUNK 256   // edge chunks for partition passes

typedef __attribute__((ext_vector_type(8))) short bf16x8;
typedef __attribute__((ext_vector_type(4))) float f32x4;

__device__ __forceinline__ unsigned short f2bf(float f) {
  union { float f; uint32_t u; } v; v.f = f;
  uint32_t u = v.u;
  uint32_t r = (u + 0x7FFFu + ((u >> 16) & 1u)) >> 16;  // RNE
  return (unsigned short)r;
}
__device__ __forceinline__ float bf_lo(uint32_t u) {
  union { uint32_t u; float f; } v; v.u = u << 16; return v.f;
}
__device__ __forceinline__ float bf_hi(uint32_t u) {
  union { uint32_t u; float f; } v; v.u = u & 0xFFFF0000u; return v.f;
}

// gemm block: 64 rows x 128 cols. kt-outer, 8 INDEPENDENT accumulators so MFMA
// chains interleave (R5's acc-reuse serialized them at VGPR_Count=64), A-chunk
// software prefetch. Verified fragment layouts (R2).
__device__ __forceinline__ void gemm_block(int bid, const float* __restrict__ x,
                                           const unsigned short* __restrict__ wt,
                                           unsigned short* __restrict__ hp, int N) {
  int wave = threadIdx.x >> 6, lane = threadIdx.x & 63;
  int m = lane & 15, q = lane >> 4;
  int r0 = bid * 64 + wave * 16;
  if (r0 >= N) return;  // N % 16 == 0
  const float* xrow = x + (size_t)(r0 + m) * D_IN + q * 8;

  f32x4 acc[8];
#pragma unroll
  for (int nt = 0; nt < 8; ++nt) acc[nt] = f32x4{0.f, 0.f, 0.f, 0.f};

  float4 u0 = *reinterpret_cast<const float4*>(xrow);
  float4 u1 = *reinterpret_cast<const float4*>(xrow + 4);
#pragma unroll
  for (int kt = 0; kt < 8; ++kt) {
    float4 n0, n1;
    if (kt < 7) {
      n0 = *reinterpret_cast<const float4*>(xrow + (kt + 1) * 32);
      n1 = *reinterpret_cast<const float4*>(xrow + (kt + 1) * 32 + 4);
    }
    bf16x8 a;
    a[0] = (short)f2bf(u0.x); a[1] = (short)f2bf(u0.y);
    a[2] = (short)f2bf(u0.z); a[3] = (short)f2bf(u0.w);
    a[4] = (short)f2bf(u1.x); a[5] = (short)f2bf(u1.y);
    a[6] = (short)f2bf(u1.z); a[7] = (short)f2bf(u1.w);
    const unsigned short* wbase = wt + q * 8 + kt * 32;
#pragma unroll
    for (int nt = 0; nt < 8; ++nt) {
      bf16x8 bv = *reinterpret_cast<const bf16x8*>(wbase + (size_t)(nt * 16 + m) * D_IN);
      acc[nt] = __builtin_amdgcn_mfma_f32_16x16x32_bf16(a, bv, acc[nt], 0, 0, 0);
    }
    u0 = n0; u1 = n1;
  }
#pragma unroll
  for (int nt = 0; nt < 8; ++nt)
#pragma unroll
    for (int r = 0; r < 4; ++r)
      hp[(size_t)(r0 + q * 4 + r) * D_OUT + nt * 16 + m] = f2bf(acc[nt][r]);
}

// K1: conv_w (blocks 0..127) + passA (blocks 128..128+NCHUNK-1). Independent.
__global__ __launch_bounds__(256) void k_prep(const float* __restrict__ W,
                                              unsigned short* __restrict__ wt,
                                              const int* __restrict__ ei, int E, int CH,
                                              int NB, int* __restrict__ cntm) {
  __shared__ int bins[MAXB];
  if (blockIdx.x < 128) {
    int idx = blockIdx.x * 256 + threadIdx.x;  // 32768 = 128*256
    int n = idx >> 8, k = idx & 255;
    wt[idx] = f2bf(W[k * D_OUT + n]);
    return;
  }
  int c = blockIdx.x - 128;
  for (int b = threadIdx.x; b < NB; b += 256) bins[b] = 0;
  __syncthreads();
  int start = c * CH, end = min(E, start + CH);
  for (int eb = start + (int)threadIdx.x * 4; eb < end; eb += 1024) {
    int kmax = end - eb; if (kmax > 4) kmax = 4;
    if (kmax == 4) {
      int4 v = *reinterpret_cast<const int4*>(ei + E + eb);
      atomicAdd(&bins[v.x >> 7], 1);
      atomicAdd(&bins[v.y >> 7], 1);
      atomicAdd(&bins[v.z >> 7], 1);
      atomicAdd(&bins[v.w >> 7], 1);
    } else {
      for (int k = 0; k < kmax; ++k) atomicAdd(&bins[ei[E + eb + k] >> 7], 1);
    }
  }
  __syncthreads();
  for (int b = threadIdx.x; b < NB; b += 256) cntm[(size_t)b * NCHUNK + c] = bins[b];
}

// K2: per bucket, exclusive scan of its NCHUNK chunk counts -> ofs, tot.
__global__ __launch_bounds__(NCHUNK) void k_scan1(const int* __restrict__ cntm,
                                                  int* __restrict__ ofs,
                                                  int* __restrict__ tot) {
  __shared__ int sc[NCHUNK];
  int b = blockIdx.x, t = threadIdx.x;
  int v = cntm[(size_t)b * NCHUNK + t];
  sc[t] = v;
  __syncthreads();
  for (int off = 1; off < NCHUNK; off <<= 1) {
    int val = (t >= off) ? sc[t - off] : 0;
    __syncthreads();
    sc[t] += val;
    __syncthreads();
  }
  ofs[(size_t)b * NCHUNK + t] = sc[t] - v;
  if (t == NCHUNK - 1) tot[b] = sc[t];
}

// K3: passC (blocks 0..NCHUNK-1, inline base-scan of tot; chunk 0 exports base)
//     + first Gg1 gemm blocks co-scheduled (independent pipes).
__global__ __launch_bounds__(256, 4) void k_place_gemm(
    const int* __restrict__ ei, int E, int CH, int NB,
    const int* __restrict__ ofs, const int* __restrict__ tot,
    int* __restrict__ basep, int* __restrict__ P,
    const float* __restrict__ x, const unsigned short* __restrict__ wt,
    unsigned short* __restrict__ hp, int N) {
  __shared__ int sc[256];
  __shared__ int cur[MAXB];
  if (blockIdx.x >= NCHUNK) {
    gemm_block(blockIdx.x - NCHUNK, x, wt, hp, N);
    return;
  }
  int c = blockIdx.x, t = threadIdx.x;
  // inline exclusive scan of bucket totals (redundant per block, ~3 KB reads)
  int v[4]; int s = 0;
#pragma unroll
  for (int j = 0; j < 4; ++j) {
    int i = t * 4 + j;
    v[j] = (i < NB) ? tot[i] : 0;
    s += v[j];
  }
  sc[t] = s;
  __syncthreads();
  for (int off = 1; off < 256; off <<= 1) {
    int val = (t >= off) ? sc[t - off] : 0;
    __syncthreads();
    sc[t] += val;
    __syncthreads();
  }
  int ex = sc[t] - s;
#pragma unroll
  for (int j = 0; j < 4; ++j) {
    int i = t * 4 + j;
    if (i < NB) cur[i] = ex + ofs[(size_t)i * NCHUNK + c];
    ex += v[j];
  }
  __syncthreads();
  if (c == 0) {  // ofs[b][0]==0, so cur==base here; export for K4
    for (int b = t; b < NB; b += 256) basep[b] = cur[b];
  }
  int start = c * CH, end = min(E, start + CH);
  for (int eb = start + t * 4; eb < end; eb += 1024) {
    int kmax = end - eb; if (kmax > 4) kmax = 4;
    int s4[4], d4[4];
    if (kmax == 4) {
      int4 vs = *reinterpret_cast<const int4*>(ei + eb);
      int4 vd = *reinterpret_cast<const int4*>(ei + E + eb);
      s4[0] = vs.x; s4[1] = vs.y; s4[2] = vs.z; s4[3] = vs.w;
      d4[0] = vd.x; d4[1] = vd.y; d4[2] = vd.z; d4[3] = vd.w;
    } else {
      for (int k = 0; k < kmax; ++k) { s4[k] = ei[eb + k]; d4[k] = ei[E + eb + k]; }
    }
#pragma unroll
    for (int k = 0; k < 4; ++k) {
      if (k >= kmax) break;
      int d = d4[k];
      int p = atomicAdd(&cur[d >> 7], 1);
      P[p] = s4[k] | ((d & 127) << 17);
    }
  }
}

// K4: sortd (blocks 0..NB-1: per-bucket counting sort -> dst-sorted CSR, nptr, dinv)
//     + remaining gemm blocks co-scheduled.
__global__ __launch_bounds__(256, 4) void k_sort_gemm(
    const int* __restrict__ P, const int* __restrict__ basep,
    const int* __restrict__ tot, int* __restrict__ nptr, float* __restrict__ dinv,
    int* __restrict__ P2, int N, int E, int NB,
    const float* __restrict__ x, const unsigned short* __restrict__ wt,
    unsigned short* __restrict__ hp, int Goff) {
  __shared__ int ideg[128];
  __shared__ int sc[128];
  __shared__ int cur[128];
  if (blockIdx.x >= (unsigned)NB) {
    gemm_block(blockIdx.x - NB + Goff, x, wt, hp, N);
    return;
  }
  int b = blockIdx.x, t = threadIdx.x;
  if (b == 0 && t == 0) nptr[N] = E;
  if (t < 128) ideg[t] = 0;
  __syncthreads();
  int s0 = basep[b], T = tot[b];
  for (int i = s0 + t; i < s0 + T; i += 256) atomicAdd(&ideg[P[i] >> 17], 1);
  __syncthreads();
  if (t < 128) sc[t] = ideg[t];
  __syncthreads();
  for (int off = 1; off < 128; off <<= 1) {
    int v = (t < 128 && t >= off) ? sc[t - off] : 0;
    __syncthreads();
    if (t < 128) sc[t] += v;
    __syncthreads();
  }
  if (t < 128) {
    int exc = s0 + sc[t] - ideg[t];
    int node = b * 128 + t;
    if (node < N) {
      nptr[node] = exc;
      dinv[node] = rsqrtf(1.0f + (float)ideg[t]);
    }
    cur[t] = exc;
  }
  __syncthreads();
  for (int i = s0 + t; i < s0 + T; i += 256) {
    int pk = P[i];
    int p = atomicAdd(&cur[pk >> 17], 1);
    P2[p] = pk & 0x1FFFF;
  }
}

// K5: one wave per node over its CSR run; lane slot j=lane>>4 takes edges rs+j+4k,
// 2 edges per slot in flight (8 outstanding 256B row-gathers/wave). Register acc,
// shfl reduce across slots, coalesced fp32 epilogue.
__global__ __launch_bounds__(256) void k_agg(const int* __restrict__ P2,
                                             const int* __restrict__ nptr,
                                             const uint4* __restrict__ hrows,
                                             const float* __restrict__ dinv,
                                             const float* __restrict__ bias,
                                             float* __restrict__ out, int N) {
  int wave = threadIdx.x >> 6, lane = threadIdx.x & 63;
  int node = blockIdx.x * 4 + wave;
  if (node >= N) return;
  int rs = nptr[node], re = nptr[node + 1];
  int j = lane >> 4, c = lane & 15;

  float acc[8];
#pragma unroll
  for (int k = 0; k < 8; ++k) acc[k] = 0.f;

  int e = rs + j;
  for (; e + 4 < re; e += 8) {
    int sA = P2[e], sB = P2[e + 4];
    float rA = dinv[sA], rB = dinv[sB];
    uint4 uA = hrows[(size_t)sA * 16 + c];
    uint4 uB = hrows[(size_t)sB * 16 + c];
    acc[0] += rA * bf_lo(uA.x) + rB * bf_lo(uB.x);
    acc[1] += rA * bf_hi(uA.x) + rB * bf_hi(uB.x);
    acc[2] += rA * bf_lo(uA.y) + rB * bf_lo(uB.y);
    acc[3] += rA * bf_hi(uA.y) + rB * bf_hi(uB.y);
    acc[4] += rA * bf_lo(uA.z) + rB * bf_lo(uB.z);
    acc[5] += rA * bf_hi(uA.z) + rB * bf_hi(uB.z);
    acc[6] += rA * bf_lo(uA.w) + rB * bf_lo(uB.w);
    acc[7] += rA * bf_hi(uA.w) + rB * bf_hi(uB.w);
  }
  if (e < re) {
    int sA = P2[e];
    float rA = dinv[sA];
    uint4 uA = hrows[(size_t)sA * 16 + c];
    acc[0] += rA * bf_lo(uA.x); acc[1] += rA * bf_hi(uA.x);
    acc[2] += rA * bf_lo(uA.y); acc[3] += rA * bf_hi(uA.y);
    acc[4] += rA * bf_lo(uA.z); acc[5] += rA * bf_hi(uA.z);
    acc[6] += rA * bf_lo(uA.w); acc[7] += rA * bf_hi(uA.w);
  }
#pragma unroll
  for (int k = 0; k < 8; ++k) {
    acc[k] += __shfl_xor(acc[k], 16);
    acc[k] += __shfl_xor(acc[k], 32);
  }
  if (j == 0) {
    float rsn = dinv[node];
    uint4 uh = hrows[(size_t)node * 16 + c];
    float self[8] = {bf_lo(uh.x), bf_hi(uh.x), bf_lo(uh.y), bf_hi(uh.y),
                     bf_lo(uh.z), bf_hi(uh.z), bf_lo(uh.w), bf_hi(uh.w)};
    const float4* b4 = reinterpret_cast<const float4*>(bias);
    float4 b0 = b4[c * 2], b1 = b4[c * 2 + 1];
    float bb[8] = {b0.x, b0.y, b0.z, b0.w, b1.x, b1.y, b1.z, b1.w};
    float o[8];
#pragma unroll
    for (int k = 0; k < 8; ++k) {
      float v = rsn * (acc[k] + rsn * self[k]) + bb[k];
      o[k] = v > 0.f ? v : 0.f;
    }
    float4* orow = reinterpret_cast<float4*>(out + (size_t)node * D_OUT + c * 8);
    orow[0] = float4{o[0], o[1], o[2], o[3]};
    orow[1] = float4{o[4], o[5], o[6], o[7]};
  }
}

extern "C" void kernel_launch(void* const* d_in, const int* in_sizes, int n_in,
                              void* d_out, int out_size, void* d_ws, size_t ws_size,
                              hipStream_t stream) {
  const float* x = (const float*)d_in[0];
  const int* ei = (const int*)d_in[1];
  const float* W = (const float*)d_in[2];
  const float* bias = (const float*)d_in[3];
  int N = in_sizes[0] / D_IN;
  int E = in_sizes[1] / 2;
  float* out = (float*)d_out;

  int NB = (N + 127) >> 7;                        // 782 buckets
  int CH = ((E + NCHUNK - 1) / NCHUNK + 3) & ~3;  // 4-aligned chunk size

  // Workspace (~41 MB): wt | hp | dinv | cntm | ofs | tot | base | nptr | P | P2
  char* w = (char*)d_ws;
  size_t off = 0;
  auto alloc = [&](size_t bytes) -> void* {
    void* p = w + off;
    off = (off + bytes + 255) & ~(size_t)255;
    return p;
  };
  unsigned short* wt = (unsigned short*)alloc((size_t)D_IN * D_OUT * 2);
  unsigned short* hp = (unsigned short*)alloc((size_t)N * D_OUT * 2);
  float* dinv = (float*)alloc((size_t)N * 4);
  int* cntm = (int*)alloc((size_t)NB * NCHUNK * 4);
  int* ofs = (int*)alloc((size_t)NB * NCHUNK * 4);
  int* tot = (int*)alloc((size_t)NB * 4);
  int* basep = (int*)alloc((size_t)NB * 4);
  int* nptr = (int*)alloc((size_t)(N + 1) * 4);
  int* P = (int*)alloc((size_t)E * 4);
  int* P2 = (int*)alloc((size_t)E * 4);
  (void)ws_size; (void)n_in; (void)out_size;

  int Gg = (N + 63) / 64;        // 1563 gemm blocks
  int Gg1 = (Gg * 3) / 5;        // co-scheduled with passC
  int Gg2 = Gg - Gg1;            // co-scheduled with sortd

  k_prep<<<128 + NCHUNK, 256, 0, stream>>>(W, wt, ei, E, CH, NB, cntm);
  k_scan1<<<NB, NCHUNK, 0, stream>>>(cntm, ofs, tot);
  k_place_gemm<<<NCHUNK + Gg1, 256, 0, stream>>>(ei, E, CH, NB, ofs, tot, basep, P,
                                                 x, wt, hp, N);
  k_sort_gemm<<<NB + Gg2, 256, 0, stream>>>(P, basep, tot, nptr, dinv, P2, N, E, NB,
                                            x, wt, hp, Gg1);
  k_agg<<<(N + 3) / 4, 256, 0, stream>>>(P2, nptr, (const uint4*)hp, dinv, bias, out, N);
}